// Round 1
// baseline (18.396 us; speedup 1.0000x reference)
//
#include <hip/hip_runtime.h>

// 4-qubit statevector sim, one thread per batch sample, state in registers.
// Qubit q <-> bit (3-q) of the flat index (C-order of (2,2,2,2)).
// RX(t) = [[cos(t/2), -i sin(t/2)], [-i sin(t/2), cos(t/2)]]

__global__ void precompute_cs(const float* __restrict__ qw, float* __restrict__ cs) {
    int i = threadIdx.x;
    if (i < 8) {
        float t = 0.5f * qw[i];
        cs[i]     = __cosf(t);
        cs[8 + i] = __sinf(t);
    }
}

template<int BQ>
__device__ __forceinline__ void rx_gate(float xr[16], float xi[16], float c, float s) {
#pragma unroll
    for (int i0 = 0; i0 < 16; ++i0) {
        if (i0 & BQ) continue;
        const int i1 = i0 | BQ;
        float x0 = xr[i0], y0 = xi[i0];
        float x1 = xr[i1], y1 = xi[i1];
        // a0' = c*a0 - i s*a1 ; a1' = -i s*a0 + c*a1   (complex, split re/im)
        xr[i0] = fmaf(c, x0,  s * y1);
        xi[i0] = fmaf(c, y0, -s * x1);
        xr[i1] = fmaf(c, x1,  s * y0);
        xi[i1] = fmaf(c, y1, -s * x0);
    }
}

template<int BC, int BT>
__device__ __forceinline__ void cnot_gate(float xr[16], float xi[16]) {
#pragma unroll
    for (int i = 0; i < 16; ++i) {
        if ((i & BC) && !(i & BT)) {
            const int j = i | BT;
            float tr = xr[i]; xr[i] = xr[j]; xr[j] = tr;
            float ti = xi[i]; xi[i] = xi[j]; xi[j] = ti;
        }
    }
}

template<bool USE_CS>
__global__ __launch_bounds__(256) void qsim_kernel(
        const float* __restrict__ inputs,
        const float* __restrict__ csorw,   // USE_CS: [8 cos | 8 sin]; else raw weights[8]
        float* __restrict__ out, int batch) {
    int b = blockIdx.x * blockDim.x + threadIdx.x;
    if (b >= batch) return;

    const float4 in4 = *reinterpret_cast<const float4*>(inputs + (size_t)b * 4);

    float t0 = 0.5f * in4.x, t1 = 0.5f * in4.y, t2 = 0.5f * in4.z, t3 = 0.5f * in4.w;
    float c0 = __cosf(t0), s0 = __sinf(t0);
    float c1 = __cosf(t1), s1 = __sinf(t1);
    float c2 = __cosf(t2), s2 = __sinf(t2);
    float c3 = __cosf(t3), s3 = __sinf(t3);

    // Layer weights' cos/sin (batch-uniform).
    float wc[8], wsn[8];
#pragma unroll
    for (int i = 0; i < 8; ++i) {
        if (USE_CS) {
            wc[i]  = csorw[i];
            wsn[i] = csorw[8 + i];
        } else {
            float t = 0.5f * csorw[i];
            wc[i]  = __cosf(t);
            wsn[i] = __sinf(t);
        }
    }

    // Product state after AngleEmbedding: |amp[idx]| = prod(c or s per bit),
    // phase = (-i)^popcount(idx). 3-level Kronecker build: 28 muls.
    float m01[4], m012[8], m[16];
    m01[0] = c0 * c1; m01[1] = c0 * s1; m01[2] = s0 * c1; m01[3] = s0 * s1;
#pragma unroll
    for (int i = 0; i < 4; ++i) { m012[2*i] = m01[i] * c2; m012[2*i+1] = m01[i] * s2; }
#pragma unroll
    for (int i = 0; i < 8; ++i) { m[2*i] = m012[i] * c3; m[2*i+1] = m012[i] * s3; }

    float xr[16], xi[16];
#pragma unroll
    for (int i = 0; i < 16; ++i) {
        const int k = __builtin_popcount((unsigned)i) & 3;   // compile-time
        xr[i] = (k == 0) ?  m[i] : (k == 2) ? -m[i] : 0.0f;
        xi[i] = (k == 1) ? -m[i] : (k == 3) ?  m[i] : 0.0f;
    }

    // BasicEntanglerLayers: per layer RX on each wire, then CNOT ring.
#pragma unroll
    for (int l = 0; l < 2; ++l) {
        rx_gate<8>(xr, xi, wc[l*4+0], wsn[l*4+0]);   // wire 0
        rx_gate<4>(xr, xi, wc[l*4+1], wsn[l*4+1]);   // wire 1
        rx_gate<2>(xr, xi, wc[l*4+2], wsn[l*4+2]);   // wire 2
        rx_gate<1>(xr, xi, wc[l*4+3], wsn[l*4+3]);   // wire 3
        cnot_gate<8,4>(xr, xi);   // CNOT(0,1)
        cnot_gate<4,2>(xr, xi);   // CNOT(1,2)
        cnot_gate<2,1>(xr, xi);   // CNOT(2,3)
        cnot_gate<1,8>(xr, xi);   // CNOT(3,0)
    }

    // PauliZ expectations on wires 0,1,2 (bit masks 8,4,2).
    float z0 = 0.f, z1 = 0.f, z2 = 0.f;
#pragma unroll
    for (int i = 0; i < 16; ++i) {
        float p = fmaf(xr[i], xr[i], xi[i] * xi[i]);
        z0 += (i & 8) ? -p : p;
        z1 += (i & 4) ? -p : p;
        z2 += (i & 2) ? -p : p;
    }

    float* o = out + (size_t)b * 3;
    o[0] = z0; o[1] = z1; o[2] = z2;
}

extern "C" void kernel_launch(void* const* d_in, const int* in_sizes, int n_in,
                              void* d_out, int out_size, void* d_ws, size_t ws_size,
                              hipStream_t stream) {
    const float* inputs = (const float*)d_in[0];   // (B, 4) f32
    const float* qw     = (const float*)d_in[1];   // (2, 4) f32
    float* out = (float*)d_out;                    // (B, 3) f32
    const int batch = in_sizes[0] / 4;

    const int block = 256;
    const int grid = (batch + block - 1) / block;

    if (ws_size >= 64) {
        float* cs = (float*)d_ws;
        precompute_cs<<<1, 64, 0, stream>>>(qw, cs);
        qsim_kernel<true><<<grid, block, 0, stream>>>(inputs, cs, out, batch);
    } else {
        qsim_kernel<false><<<grid, block, 0, stream>>>(inputs, qw, out, batch);
    }
}

// Round 2
// 16.988 us; speedup vs baseline: 1.0829x; 1.0829x over previous
//
#include <hip/hip_runtime.h>

// 4-qubit statevector sim, one thread per batch sample, state in registers.
// Qubit q <-> bit (3-q) of the flat index (C-order of (2,2,2,2)).
// RX(t) = [[cos(t/2), -i sin(t/2)], [-i sin(t/2), cos(t/2)]]
//
// Key algebraic merge: AngleEmbedding RX(x_q) is immediately followed by
// layer-0's RX(w0q) on the same wire -> RX(x_q + w0q). So the state after
// "embedding + layer-0 RX" is a PRODUCT state with angles (x_q+w0q)/2,
// built by a 28-mul Kronecker + compile-time (-i)^popcount phase signs.
// Remaining circuit: CNOT ring (register renames, free), RX(w1q) x4,
// CNOT ring (free), |amp|^2 -> Z expectations.

template<int BQ>
__device__ __forceinline__ void rx_gate(float xr[16], float xi[16], float c, float s) {
#pragma unroll
    for (int i0 = 0; i0 < 16; ++i0) {
        if (i0 & BQ) continue;
        const int i1 = i0 | BQ;
        float x0 = xr[i0], y0 = xi[i0];
        float x1 = xr[i1], y1 = xi[i1];
        // a0' = c*a0 - i s*a1 ; a1' = -i s*a0 + c*a1   (complex, split re/im)
        xr[i0] = fmaf(c, x0,  s * y1);
        xi[i0] = fmaf(c, y0, -s * x1);
        xr[i1] = fmaf(c, x1,  s * y0);
        xi[i1] = fmaf(c, y1, -s * x0);
    }
}

template<int BC, int BT>
__device__ __forceinline__ void cnot_gate(float xr[16], float xi[16]) {
#pragma unroll
    for (int i = 0; i < 16; ++i) {
        if ((i & BC) && !(i & BT)) {
            const int j = i | BT;
            float tr = xr[i]; xr[i] = xr[j]; xr[j] = tr;
            float ti = xi[i]; xi[i] = xi[j]; xi[j] = ti;
        }
    }
}

__global__ __launch_bounds__(256) void qsim_kernel(
        const float* __restrict__ inputs,
        const float* __restrict__ qw,      // (2,4) f32, batch-uniform
        float* __restrict__ out, int batch) {
    int b = blockIdx.x * blockDim.x + threadIdx.x;
    if (b >= batch) return;

    const float4 in4 = *reinterpret_cast<const float4*>(inputs + (size_t)b * 4);

    // Merged half-angles (embedding + layer-0 weights). qw[] loads are
    // wave-uniform -> scalar loads.
    float t0 = 0.5f * (in4.x + qw[0]);
    float t1 = 0.5f * (in4.y + qw[1]);
    float t2 = 0.5f * (in4.z + qw[2]);
    float t3 = 0.5f * (in4.w + qw[3]);
    float c0 = __cosf(t0), s0 = __sinf(t0);
    float c1 = __cosf(t1), s1 = __sinf(t1);
    float c2 = __cosf(t2), s2 = __sinf(t2);
    float c3 = __cosf(t3), s3 = __sinf(t3);

    // Layer-1 weight half-angle trig (uniform values, cheap: 8 trans ops).
    float wc[4], wsn[4];
#pragma unroll
    for (int q = 0; q < 4; ++q) {
        float t = 0.5f * qw[4 + q];
        wc[q]  = __cosf(t);
        wsn[q] = __sinf(t);
    }

    // Product state magnitudes: 3-level Kronecker, 28 muls.
    float m01[4], m012[8], m[16];
    m01[0] = c0 * c1; m01[1] = c0 * s1; m01[2] = s0 * c1; m01[3] = s0 * s1;
#pragma unroll
    for (int i = 0; i < 4; ++i) { m012[2*i] = m01[i] * c2; m012[2*i+1] = m01[i] * s2; }
#pragma unroll
    for (int i = 0; i < 8; ++i) { m[2*i] = m012[i] * c3; m[2*i+1] = m012[i] * s3; }

    // amp[idx] = (-i)^popcount(idx) * m[idx]
    float xr[16], xi[16];
#pragma unroll
    for (int i = 0; i < 16; ++i) {
        const int k = __builtin_popcount((unsigned)i) & 3;   // compile-time
        xr[i] = (k == 0) ?  m[i] : (k == 2) ? -m[i] : 0.0f;
        xi[i] = (k == 1) ? -m[i] : (k == 3) ?  m[i] : 0.0f;
    }

    // Layer 0 CNOT ring (free renames).
    cnot_gate<8,4>(xr, xi);   // CNOT(0,1)
    cnot_gate<4,2>(xr, xi);   // CNOT(1,2)
    cnot_gate<2,1>(xr, xi);   // CNOT(2,3)
    cnot_gate<1,8>(xr, xi);   // CNOT(3,0)

    // Layer 1 RX gates.
    rx_gate<8>(xr, xi, wc[0], wsn[0]);
    rx_gate<4>(xr, xi, wc[1], wsn[1]);
    rx_gate<2>(xr, xi, wc[2], wsn[2]);
    rx_gate<1>(xr, xi, wc[3], wsn[3]);

    // Layer 1 CNOT ring (free renames).
    cnot_gate<8,4>(xr, xi);
    cnot_gate<4,2>(xr, xi);
    cnot_gate<2,1>(xr, xi);
    cnot_gate<1,8>(xr, xi);

    // PauliZ expectations on wires 0,1,2 (bit masks 8,4,2).
    float z0 = 0.f, z1 = 0.f, z2 = 0.f;
#pragma unroll
    for (int i = 0; i < 16; ++i) {
        float p = fmaf(xr[i], xr[i], xi[i] * xi[i]);
        z0 += (i & 8) ? -p : p;
        z1 += (i & 4) ? -p : p;
        z2 += (i & 2) ? -p : p;
    }

    float* o = out + (size_t)b * 3;
    o[0] = z0; o[1] = z1; o[2] = z2;
}

extern "C" void kernel_launch(void* const* d_in, const int* in_sizes, int n_in,
                              void* d_out, int out_size, void* d_ws, size_t ws_size,
                              hipStream_t stream) {
    const float* inputs = (const float*)d_in[0];   // (B, 4) f32
    const float* qw     = (const float*)d_in[1];   // (2, 4) f32
    float* out = (float*)d_out;                    // (B, 3) f32
    const int batch = in_sizes[0] / 4;

    const int block = 256;
    const int grid = (batch + block - 1) / block;
    qsim_kernel<<<grid, block, 0, stream>>>(inputs, qw, out, batch);
}

// Round 3
// 10.273 us; speedup vs baseline: 1.7907x; 1.6536x over previous
//
#include <hip/hip_runtime.h>

// Analytic closed form of the 4-qubit circuit (AngleEmbedding RX + 2x
// BasicEntanglerLayers with CNOT ring), derived via Heisenberg-picture Pauli
// propagation. With a_q = x_q + w0_q (embedding RX merged with layer-0 RX,
// same axis) and b_q = w1_q, conjugating Z0/Z1/Z2 back through
// C2 R2 C1 R1 |0000> leaves only Pauli strings with no X/Y factors:
//
//   <Z0> = ca0*(U1*A + U2*B) + sa0*(U3*B + U4*A)
//   <Z1> = ca3*(V1*ca0*ca2 + V2*sa0*sa2)
//   <Z2> = P1*A + P2*B
//
//   A = ca1*ca3, B = sa1*sa3,  ca_q = cos(a_q), sa_q = sin(a_q)  [FULL angle]
//   U1 = cb1*cb2*cb3, U2 = sb1*sb2*cb3, U3 = cb1*cb2*sb3, U4 = sb1*sb2*sb3
//   V1 = cb0*cb1, V2 = sb0*sb1, P1 = cb0*cb1*cb2, P2 = cb0*sb1*sb2
//
// Verified symbolically + at 8 numeric corner/superposition cases against the
// direct statevector simulation (incl. the YYY cross terms).

__global__ __launch_bounds__(256) void qexp_kernel(
        const float* __restrict__ inputs,
        const float* __restrict__ qw,      // (2,4) f32: [w0_0..w0_3, w1_0..w1_3]
        float* __restrict__ out, int batch) {
    int b = blockIdx.x * blockDim.x + threadIdx.x;
    if (b >= batch) return;

    const float4 in4 = *reinterpret_cast<const float4*>(inputs + (size_t)b * 4);

    // Batch-uniform layer-1 trig (full angles) and coefficient products.
    float sb0, cb0, sb1, cb1, sb2, cb2, sb3, cb3;
    __sincosf(qw[4], &sb0, &cb0);
    __sincosf(qw[5], &sb1, &cb1);
    __sincosf(qw[6], &sb2, &cb2);
    __sincosf(qw[7], &sb3, &cb3);
    const float Pu = cb1 * cb2, Qu = sb1 * sb2;
    const float U1 = Pu * cb3, U2 = Qu * cb3, U3 = Pu * sb3, U4 = Qu * sb3;
    const float V1 = cb0 * cb1, V2 = sb0 * sb1;
    const float P1 = cb0 * Pu,  P2 = cb0 * Qu;

    // Per-sample merged full angles a_q = x_q + w0_q.
    float sa0, ca0, sa1, ca1, sa2, ca2, sa3, ca3;
    __sincosf(in4.x + qw[0], &sa0, &ca0);
    __sincosf(in4.y + qw[1], &sa1, &ca1);
    __sincosf(in4.z + qw[2], &sa2, &ca2);
    __sincosf(in4.w + qw[3], &sa3, &ca3);

    const float A = ca1 * ca3;
    const float B = sa1 * sa3;

    const float z0 = fmaf(sa0, fmaf(U3, B, U4 * A), ca0 * fmaf(U1, A, U2 * B));
    const float z1 = ca3 * fmaf(V1, ca0 * ca2, V2 * (sa0 * sa2));
    const float z2 = fmaf(P1, A, P2 * B);

    float* o = out + (size_t)b * 3;
    o[0] = z0; o[1] = z1; o[2] = z2;
}

extern "C" void kernel_launch(void* const* d_in, const int* in_sizes, int n_in,
                              void* d_out, int out_size, void* d_ws, size_t ws_size,
                              hipStream_t stream) {
    const float* inputs = (const float*)d_in[0];   // (B, 4) f32
    const float* qw     = (const float*)d_in[1];   // (2, 4) f32
    float* out = (float*)d_out;                    // (B, 3) f32
    const int batch = in_sizes[0] / 4;

    const int block = 256;
    const int grid = (batch + block - 1) / block;
    qexp_kernel<<<grid, block, 0, stream>>>(inputs, qw, out, batch);
}